// Round 10
// baseline (268.975 us; speedup 1.0000x reference)
//
#include <hip/hip_runtime.h>

// MS-G3D block. bf16-MFMA k1, t-chunk=2, dt SPLIT ACROSS WAVES (12 waves).
// Nine rounds showed k1 invariant (~91us) under three orthogonal per-wave
// stall reductions; counters (Mfma 15%, VALU 18%, Occ 16%, HBM 4%) say
// insufficient parallelism at the never-varied 12 waves/CU. This rev doubles
// TLP: 768 threads, wave=(wo,dt) each running the round-8-proven per-dt
// pipeline (GEMM1' swapped -> pack -> b64 write -> fence -> GEMM2) with a
// private tmp2 tile. LDS 64,768B -> 2 blocks/CU = 24 waves/CU (6/SIMD).
// launch_bounds(768,6) caps VGPR at 85 (round-8 body was 84 with 2x the
// accumulator state -> fits). Round-9 absbuf staging reverted (it hurt).
// Packing stays manual f2bf|f2bf<<16 (cvt_pk operand order = rounds 5-7 bug).
// N=8, C=96, T=128, V=25, WIN=3, VL=75, NS=6.

#define NB 8
#define CB 96
#define TB 128
#define VB 25
#define VLB 75
#define EPSB 1e-5f
#define XRS 104   // xraw row stride (shorts)
#define T2S 104   // tmp2 row stride (shorts)
#define HBS 296   // hnb row stride (shorts)

typedef __attribute__((ext_vector_type(8))) short bf16x8;
typedef __attribute__((ext_vector_type(4))) short short4v;
typedef __attribute__((ext_vector_type(4))) float f32x4;
typedef __attribute__((ext_vector_type(2))) unsigned int uint2v;
typedef __attribute__((ext_vector_type(4))) unsigned int uint4v;

__device__ inline unsigned short f2bf(float f) {
  unsigned int u = __float_as_uint(f);
  u = (u + 0x7FFFu + ((u >> 16) & 1u)) >> 16;
  return (unsigned short)u;
}
__device__ inline float bf2f(unsigned short u) {
  return __uint_as_float(((unsigned int)u) << 16);
}
__device__ inline unsigned pack2bf(float lo, float hi) {
  return (unsigned)f2bf(lo) | ((unsigned)f2bf(hi) << 16);
}

// ---------------- K0: build fragment-swizzled bf16 weights; zero stats -------
// Wsw  [ps][wo][kk][lane][j] : W_ps[o=wo*16+(l&15)][c=kk*32+(l>>4)*8+j]
// ABsw [ps][nt][kk][lane][j] : AB_ps[u=nt*16+(l&15)][u'=kk*32+(l>>4)*8+j]
// Wosw [wv][kk][lane][j]     : Wo[o=wv*16+(l&15)][k=kk*32+(l>>4)*8+j]
__global__ __launch_bounds__(256) void k0_init(
    const float* __restrict__ As, const float* __restrict__ Bs,
    const float* __restrict__ Ar, const float* __restrict__ Wm,
    const float* __restrict__ Wo,
    unsigned short* __restrict__ ABsw, unsigned short* __restrict__ Wsw,
    unsigned short* __restrict__ Wosw, float* __restrict__ stats) {
  int i = blockIdx.x * 256 + threadIdx.x;
  if (i < 110592) {                     // Wsw: 12*6*3*512
    int ps = i / 9216, r = i % 9216;
    int wv = r / 1536, r2 = r % 1536;
    int kk = r2 / 512, r3 = r2 % 512;
    int lane = r3 / 8, j = r3 % 8;
    int o = wv * 16 + (lane & 15);
    int c = kk * 32 + (lane >> 4) * 8 + j;
    Wsw[i] = f2bf(Wm[o * 1152 + ps * 96 + c]);
  }
  if (i < 92160) {                      // ABsw: 12*5*3*512
    int ps = i / 7680, r = i % 7680;
    int nt = r / 1536, r2 = r % 1536;
    int kk = r2 / 512, r3 = r2 % 512;
    int lane = r3 / 8, j = r3 % 8;
    int u = nt * 16 + (lane & 15);
    int up = kk * 32 + (lane >> 4) * 8 + j;
    float v = 0.f;
    if (u < 75 && up < 75) {
      int path = ps / 6, s = ps % 6;
      int idx = (s * 75 + u) * 75 + up;
      v = (path == 0 ? As[idx] : Bs[idx]) + Ar[idx];
    }
    ABsw[i] = f2bf(v);
  }
  if (i < 27648) {                      // Wosw: 6*9*512
    int wv = i / 4608, r = i % 4608;
    int kk = r / 512, r3 = r % 512;
    int lane = r3 / 8, j = r3 % 8;
    int o = wv * 16 + (lane & 15);
    int k = kk * 32 + (lane >> 4) * 8 + j;
    Wosw[i] = f2bf(Wo[o * 288 + k]);
  }
  if (i < 384) stats[i] = 0.f;
}

// ---------------- K1: t2 fused (MLP -> agg) x12 MFMA, 12 waves ---------------
// grid = N*T/2 = 512 blocks, 768 threads. wave = wo*2+dt: wo owns o-rows
// [16wo,16wo+16), dt owns t = t0+dt. Each wave: per ps, GEMM1'(one dt) ->
// pack -> ds_write_b64 x5 -> fence -> GEMM2 -> fence. Private tmp2[wave].
__global__ __launch_bounds__(768, 6) void k1t2(
    const float* __restrict__ x, const unsigned short* __restrict__ ABsw,
    const unsigned short* __restrict__ Wsw, const float* __restrict__ bm,
    unsigned short* __restrict__ h_relu, float* __restrict__ stats1) {
  __shared__ unsigned short xraw[112 * XRS];      // 23,296 B
  __shared__ unsigned short tmp2[12][16 * T2S];   // 39,936 B [wave][o16][u']
  __shared__ float st1s[2][96], st2s[2][96];      //  1,536 B  (total 64,768 B)
  const int tid = threadIdx.x;
  const int n = blockIdx.x >> 6, t0 = (blockIdx.x & 63) * 2;
  const int wave = tid >> 6, lane = tid & 63;
  const int wo = wave >> 1, dt = wave & 1;
  const int l15 = lane & 15, quad = lane >> 4, q8 = quad * 8;

  // stage raw x slice: tt = t0-1 .. t0+2 (100 rows), zero-pad rows to 112
  for (int idx = tid; idx < 96 * 112; idx += 768) {
    int c = idx / 112, r = idx - c * 112;
    float v = 0.f;
    if (r < 100) {
      int tt = t0 - 1 + r / 25, vv = r % 25;
      if (tt >= 0 && tt < TB) v = x[((n * CB + c) * TB + tt) * VB + vv];
    }
    xraw[r * XRS + c] = f2bf(v);
  }
  // zero tmp2 cols u' in [80,96) (read by GEMM2 kk=2, never written by GEMM1;
  // ABsw cols u'>=75 are zero but uninitialized LDS could be NaN -> must zero)
  for (int idx = tid; idx < 12 * 256; idx += 768) {
    int w = idx >> 8, e = idx & 255;      // e = o*16 + (u'-80)
    tmp2[w][(e >> 4) * T2S + 80 + (e & 15)] = 0;
  }
  __syncthreads();

  const f32x4 zf = {0.f, 0.f, 0.f, 0.f};
  f32x4 acc2[5];   // [nt]: D[o][u], lane: u = nt*16+l15, o = 16wo+4q+r
#pragma unroll
  for (int nt = 0; nt < 5; ++nt) acc2[nt] = zf;

  const unsigned short* Wbase = Wsw + wo * 1536 + lane * 8;   // + ps*9216 + kk*512
  const unsigned short* Bbase = ABsw + lane * 8;              // + ps*7680 + (nt*3+kk)*512
  unsigned short* tw = &tmp2[wave][l15 * T2S + quad * 4];     // b64 store base
  const unsigned short* tr = &tmp2[wave][l15 * T2S + q8];     // b128 read base
  const int xoff = dt * 25;   // xraw row offset for this wave's t

#pragma unroll
  for (int ps = 0; ps < 12; ++ps) {
    bf16x8 wa[3];
#pragma unroll
    for (int kk = 0; kk < 3; ++kk)
      wa[kk] = *reinterpret_cast<const bf16x8*>(Wbase + ps * 9216 + kk * 512);
    bf16x8 bf[15];
#pragma unroll
    for (int i = 0; i < 15; ++i)
      bf[i] = *reinterpret_cast<const bf16x8*>(Bbase + ps * 7680 + i * 512);

    // GEMM1' (SWAPPED operands): D'[u'][o16], u' = nt*16+4q+r, o16 = l15
    f32x4 acc1[5];
#pragma unroll
    for (int nt = 0; nt < 5; ++nt) acc1[nt] = zf;
#pragma unroll
    for (int kk = 0; kk < 3; ++kk)
#pragma unroll
      for (int nt = 0; nt < 5; ++nt) {
        bf16x8 a = *reinterpret_cast<const bf16x8*>(&xraw[(xoff + nt * 16 + l15) * XRS + kk * 32 + q8]);
        acc1[nt] = __builtin_amdgcn_mfma_f32_16x16x32_bf16(a, wa[kk], acc1[nt], 0, 0, 0);
      }
#pragma unroll
    for (int nt = 0; nt < 5; ++nt) {
      unsigned p01 = pack2bf(acc1[nt][0], acc1[nt][1]);
      unsigned p23 = pack2bf(acc1[nt][2], acc1[nt][3]);
      *reinterpret_cast<short4v*>(tw + nt * 16) =
          __builtin_bit_cast(short4v, (uint2v){p01, p23});
    }
    // RAW fence: tmp2 writes before GEMM2 reads (compiler ordering; HW in-order)
    asm volatile("" ::: "memory");
    __builtin_amdgcn_sched_barrier(0);

    // GEMM2 (original orientation): D[o][u] += tmp[o][u'] AB[u][u']
#pragma unroll
    for (int kk = 0; kk < 3; ++kk) {
      bf16x8 a0 = *reinterpret_cast<const bf16x8*>(tr + kk * 32);
#pragma unroll
      for (int nt = 0; nt < 5; ++nt)
        acc2[nt] = __builtin_amdgcn_mfma_f32_16x16x32_bf16(a0, bf[nt * 3 + kk], acc2[nt], 0, 0, 0);
    }
    // WAR fence: next ps's writes must not hoist above these reads
    asm volatile("" ::: "memory");
    __builtin_amdgcn_sched_barrier(0);
  }

  // epilogue: o = 16wo+4q+r rows in regs, u = nt*16+l15, t = t0+dt.
  // HR layout = hnb layout: [n][t][vv][i*3+w], slice 7200 shorts per t.
  const int orow = wo * 16 + quad * 4;
  float s1[4] = {0.f, 0.f, 0.f, 0.f}, s2[4] = {0.f, 0.f, 0.f, 0.f};
  unsigned short* hp = h_relu + (unsigned)(n * TB + t0) * 7200 + dt * 7200;
#pragma unroll
  for (int r = 0; r < 4; ++r) {
    const int o = orow + r;
    const float bias = bm[o];
#pragma unroll
    for (int nt = 0; nt < 5; ++nt) {
      int u = nt * 16 + l15;
      if (u < VLB) {
        float v = acc2[nt][r] + bias;
        v = v > 0.f ? v : 0.f;
        int w = u / 25, vv = u - w * 25;
        hp[vv * 288 + o * 3 + w] = f2bf(v);
        s1[r] += v;
        s2[r] += v * v;
      }
    }
  }
#pragma unroll
  for (int off = 1; off < 16; off <<= 1) {
#pragma unroll
    for (int r = 0; r < 4; ++r) {
      s1[r] += __shfl_xor(s1[r], off, 64);
      s2[r] += __shfl_xor(s2[r], off, 64);
    }
  }
  if (l15 == 0) {
#pragma unroll
    for (int r = 0; r < 4; ++r) { st1s[dt][orow + r] = s1[r]; st2s[dt][orow + r] = s2[r]; }
  }
  __syncthreads();
  if (tid < 96) {
    atomicAdd(&stats1[tid], st1s[0][tid] + st1s[1][tid]);
    atomicAdd(&stats1[96 + tid], st2s[0][tid] + st2s[1][tid]);
  }
}

// ---------------- K3: BN1-finalize + relu + out_conv (MFMA, 2 t/blk) --------
// grid = N*T/2 = 512 blocks. HR is already in hnb layout: staging is a linear
// b128-load -> BN+relu -> b128 LDS-write copy (no scatter).
__global__ __launch_bounds__(384) void k3n(
    const unsigned short* __restrict__ h_relu, const float* __restrict__ stats1,
    const float* __restrict__ g1, const float* __restrict__ bt1,
    const unsigned short* __restrict__ Wosw, const float* __restrict__ bo,
    float* __restrict__ out_pre) {
  __shared__ unsigned short hnb[2][32 * HBS];
  __shared__ float a1s[96], b1s[96];
  const int tid = threadIdx.x;
  const int n = blockIdx.x >> 6, t0 = (blockIdx.x & 63) * 2;

  if (tid < 96) {
    const float inv = 1.f / (8.f * 128.f * 75.f);
    float m = stats1[tid] * inv;
    float var = stats1[96 + tid] * inv - m * m;
    float a = g1[tid] * rsqrtf(var + EPSB);
    a1s[tid] = a;
    b1s[tid] = bt1[tid] - m * a;
  }
  for (int idx = tid; idx < 2 * 7 * HBS; idx += 384) {
    int d = idx / (7 * HBS), rm = idx % (7 * HBS);
    hnb[d][25 * HBS + rm] = 0;
  }
  __syncthreads();

  // linear staging: 14400 contiguous shorts; 288 % 8 == 0 so a b128 group
  // never straddles an hnb row; (vv*HBS + c)*2 is 16B-aligned (HBS=296=37*8).
  const unsigned short* hp = h_relu + (unsigned)(n * TB + t0) * 7200;
  for (int i8 = tid; i8 < 1800; i8 += 384) {
    bf16x8 v = *reinterpret_cast<const bf16x8*>(hp + i8 * 8);
    int e = i8 * 8;
    int d = e / 7200;
    int er = e - d * 7200;
    int vv = er / 288, c = er - vv * 288;
    float f[8];
#pragma unroll
    for (int j = 0; j < 8; ++j) {
      int ic = (c + j) / 3;
      float val = a1s[ic] * bf2f((unsigned short)v[j]) + b1s[ic];
      f[j] = val > 0.f ? val : 0.f;
    }
    unsigned dw0 = pack2bf(f[0], f[1]);
    unsigned dw1 = pack2bf(f[2], f[3]);
    unsigned dw2 = pack2bf(f[4], f[5]);
    unsigned dw3 = pack2bf(f[6], f[7]);
    *reinterpret_cast<uint4v*>(&hnb[d][vv * HBS + c]) = (uint4v){dw0, dw1, dw2, dw3};
  }
  __syncthreads();

  const int wave = tid >> 6, lane = tid & 63;
  const int l15 = lane & 15, quad = lane >> 4, q8 = quad * 8;
  const f32x4 zf = {0.f, 0.f, 0.f, 0.f};
  f32x4 acc[2][2] = {{zf, zf}, {zf, zf}};
  const unsigned short* Apw = Wosw + wave * 4608 + lane * 8;
#pragma unroll
  for (int kk = 0; kk < 9; ++kk) {
    bf16x8 a = *reinterpret_cast<const bf16x8*>(Apw + kk * 512);
#pragma unroll
    for (int d = 0; d < 2; ++d) {
      bf16x8 b0 = *reinterpret_cast<const bf16x8*>(&hnb[d][l15 * HBS + kk * 32 + q8]);
      bf16x8 b1 = *reinterpret_cast<const bf16x8*>(&hnb[d][(16 + l15) * HBS + kk * 32 + q8]);
      acc[d][0] = __builtin_amdgcn_mfma_f32_16x16x32_bf16(a, b0, acc[d][0], 0, 0, 0);
      acc[d][1] = __builtin_amdgcn_mfma_f32_16x16x32_bf16(a, b1, acc[d][1], 0, 0, 0);
    }
  }

  const int orow = wave * 16 + quad * 4;
#pragma unroll
  for (int d = 0; d < 2; ++d) {
#pragma unroll
    for (int nt = 0; nt < 2; ++nt) {
      int v = nt * 16 + l15;
      if (v < VB) {
#pragma unroll
        for (int r = 0; r < 4; ++r) {
          const int o = orow + r;
          out_pre[((n * CB + o) * TB + t0 + d) * VB + v] = acc[d][nt][r] + bo[o];
        }
      }
    }
  }
}

// ---------------- K4: BN2 stats (coalesced float4 reduction) ----------------
__global__ __launch_bounds__(256) void k4_stats(
    const float* __restrict__ out_pre, float* __restrict__ stats2) {
  __shared__ float ws1[4], ws2[4];
  const int tid = threadIdx.x;
  const int o = blockIdx.x % CB, p = blockIdx.x / CB;
  float s1 = 0.f, s2 = 0.f;
#pragma unroll
  for (int k = 0; k < 2; ++k) {
    const int n = 2 * p + k;
    const f32x4* base = reinterpret_cast<const f32x4*>(out_pre + (n * CB + o) * (TB * VB));
    for (int idx = tid; idx < TB * VB / 4; idx += 256) {
      f32x4 v = base[idx];
#pragma unroll
      for (int j = 0; j < 4; ++j) { s1 += v[j]; s2 += v[j] * v[j]; }
    }
  }
#pragma unroll
  for (int off = 1; off < 64; off <<= 1) {
    s1 += __shfl_xor(s1, off, 64);
    s2 += __shfl_xor(s2, off, 64);
  }
  const int wave = tid >> 6;
  if ((tid & 63) == 0) { ws1[wave] = s1; ws2[wave] = s2; }
  __syncthreads();
  if (tid == 0) {
    float r1 = ws1[0] + ws1[1] + ws1[2] + ws1[3];
    float r2 = ws2[0] + ws2[1] + ws2[2] + ws2[3];
    atomicAdd(&stats2[o], r1);
    atomicAdd(&stats2[96 + o], r2);
  }
}

// ---------------- K5: BN2 finalize (float4 elementwise) ----------------
__global__ __launch_bounds__(256) void k5_bn2(
    const float* __restrict__ out_pre, const float* __restrict__ stats2,
    const float* __restrict__ g2, const float* __restrict__ bt2,
    float* __restrict__ out) {
  int idx = blockIdx.x * 256 + threadIdx.x;
  if (idx >= NB * CB * TB * VB / 4) return;
  int o = (idx / (TB * VB / 4)) % CB;
  const float inv = 1.f / (8.f * 128.f * 25.f);
  float m = stats2[o] * inv;
  float var = stats2[96 + o] * inv - m * m;
  float a = g2[o] * rsqrtf(var + EPSB);
  float b = bt2[o] - m * a;
  f32x4 vin = reinterpret_cast<const f32x4*>(out_pre)[idx];
  f32x4 vo;
#pragma unroll
  for (int j = 0; j < 4; ++j) vo[j] = a * vin[j] + b;
  reinterpret_cast<f32x4*>(out)[idx] = vo;
}

extern "C" void kernel_launch(void* const* d_in, const int* in_sizes, int n_in,
                              void* d_out, int out_size, void* d_ws, size_t ws_size,
                              hipStream_t stream) {
  const float* x   = (const float*)d_in[0];
  const float* As  = (const float*)d_in[1];
  const float* Bs  = (const float*)d_in[2];
  const float* Ar  = (const float*)d_in[3];
  const float* Wm  = (const float*)d_in[4];
  const float* bm  = (const float*)d_in[5];
  const float* g1  = (const float*)d_in[6];
  const float* bt1 = (const float*)d_in[7];
  const float* Wo  = (const float*)d_in[8];
  const float* bo  = (const float*)d_in[9];
  const float* g2  = (const float*)d_in[10];
  const float* bt2 = (const float*)d_in[11];
  float* out = (float*)d_out;

  char* base = (char*)d_ws;
  unsigned short* HR   = (unsigned short*)base;                  // 14,745,600 B
  float* out_pre       = (float*)(base + 14745600);              //  9,830,400 B
  unsigned short* ABsw = (unsigned short*)(base + 24576000);     //    184,320 B
  unsigned short* Wsw  = (unsigned short*)(base + 24760320);     //    221,184 B
  unsigned short* Wosw = (unsigned short*)(base + 24981504);     //     55,296 B
  float* stats         = (float*)(base + 25036800);              //      1,536 B
  float* stats1 = stats, *stats2 = stats + 192;

  k0_init<<<432, 256, 0, stream>>>(As, Bs, Ar, Wm, Wo, ABsw, Wsw, Wosw, stats);
  k1t2<<<NB * TB / 2, 768, 0, stream>>>(x, ABsw, Wsw, bm, HR, stats1);
  k3n<<<NB * TB / 2, 384, 0, stream>>>(HR, stats1, g1, bt1, Wosw, bo, out_pre);
  k4_stats<<<CB * 4, 256, 0, stream>>>(out_pre, stats2);
  k5_bn2<<<(NB * CB * TB * VB / 4 + 255) / 256, 256, 0, stream>>>(out_pre, stats2, g2, bt2, out);
}

// Round 11
// 198.727 us; speedup vs baseline: 1.3535x; 1.3535x over previous
//
#include <hip/hip_runtime.h>

// MS-G3D block. bf16-MFMA k1, t-chunk=1 (grid 1024 = 4 blocks/CU).
// Ten rounds of per-wave stall reduction left k1 at ~91us; the missed fact:
// grid was 512 blocks = exactly 2/CU on 256 CUs -- occupancy was GRID-limited.
// Round 10 proved the scheduler co-residents more waves (54% occ) but its
// forced launch_bounds spilled (VGPR 40, 290MB scratch). This rev doubles TLP
// the clean way: t-chunk=1 -> 1024 blocks, 37,376B LDS -> 4 blocks/CU = 24
// waves/CU, with the round-8-proven 6-wave body (natural VGPR ~70, no forced
// occupancy). Per-block: GEMM1'(swapped)->pack->b64 write->fence->GEMM2.
// Packing stays manual f2bf|f2bf<<16 (cvt_pk operand order = rounds 5-7 bug).
// N=8, C=96, T=128, V=25, WIN=3, VL=75, NS=6.

#define NB 8
#define CB 96
#define TB 128
#define VB 25
#define VLB 75
#define EPSB 1e-5f
#define XRS 104   // xraw row stride (shorts)
#define T2S 104   // tmp2 row stride (shorts)
#define HBS 296   // hnb row stride (shorts)

typedef __attribute__((ext_vector_type(8))) short bf16x8;
typedef __attribute__((ext_vector_type(4))) short short4v;
typedef __attribute__((ext_vector_type(4))) float f32x4;
typedef __attribute__((ext_vector_type(2))) unsigned int uint2v;
typedef __attribute__((ext_vector_type(4))) unsigned int uint4v;

__device__ inline unsigned short f2bf(float f) {
  unsigned int u = __float_as_uint(f);
  u = (u + 0x7FFFu + ((u >> 16) & 1u)) >> 16;
  return (unsigned short)u;
}
__device__ inline float bf2f(unsigned short u) {
  return __uint_as_float(((unsigned int)u) << 16);
}
__device__ inline unsigned pack2bf(float lo, float hi) {
  return (unsigned)f2bf(lo) | ((unsigned)f2bf(hi) << 16);
}

// ---------------- K0: build fragment-swizzled bf16 weights; zero stats -------
// Wsw  [ps][wo][kk][lane][j] : W_ps[o=wo*16+(l&15)][c=kk*32+(l>>4)*8+j]
// ABsw [ps][nt][kk][lane][j] : AB_ps[u=nt*16+(l&15)][u'=kk*32+(l>>4)*8+j]
// Wosw [wv][kk][lane][j]     : Wo[o=wv*16+(l&15)][k=kk*32+(l>>4)*8+j]
__global__ __launch_bounds__(256) void k0_init(
    const float* __restrict__ As, const float* __restrict__ Bs,
    const float* __restrict__ Ar, const float* __restrict__ Wm,
    const float* __restrict__ Wo,
    unsigned short* __restrict__ ABsw, unsigned short* __restrict__ Wsw,
    unsigned short* __restrict__ Wosw, float* __restrict__ stats) {
  int i = blockIdx.x * 256 + threadIdx.x;
  if (i < 110592) {                     // Wsw: 12*6*3*512
    int ps = i / 9216, r = i % 9216;
    int wv = r / 1536, r2 = r % 1536;
    int kk = r2 / 512, r3 = r2 % 512;
    int lane = r3 / 8, j = r3 % 8;
    int o = wv * 16 + (lane & 15);
    int c = kk * 32 + (lane >> 4) * 8 + j;
    Wsw[i] = f2bf(Wm[o * 1152 + ps * 96 + c]);
  }
  if (i < 92160) {                      // ABsw: 12*5*3*512
    int ps = i / 7680, r = i % 7680;
    int nt = r / 1536, r2 = r % 1536;
    int kk = r2 / 512, r3 = r2 % 512;
    int lane = r3 / 8, j = r3 % 8;
    int u = nt * 16 + (lane & 15);
    int up = kk * 32 + (lane >> 4) * 8 + j;
    float v = 0.f;
    if (u < 75 && up < 75) {
      int path = ps / 6, s = ps % 6;
      int idx = (s * 75 + u) * 75 + up;
      v = (path == 0 ? As[idx] : Bs[idx]) + Ar[idx];
    }
    ABsw[i] = f2bf(v);
  }
  if (i < 27648) {                      // Wosw: 6*9*512
    int wv = i / 4608, r = i % 4608;
    int kk = r / 512, r3 = r % 512;
    int lane = r3 / 8, j = r3 % 8;
    int o = wv * 16 + (lane & 15);
    int k = kk * 32 + (lane >> 4) * 8 + j;
    Wosw[i] = f2bf(Wo[o * 288 + k]);
  }
  if (i < 384) stats[i] = 0.f;
}

// ---------------- K1: t1 fused (MLP -> agg) x12 MFMA -------------------------
// grid = N*T = 1024 blocks, 384 threads (6 waves), 4 blocks/CU (LDS 37,376B).
// Wave wo owns o-rows [16wo,16wo+16); block owns one t.
__global__ __launch_bounds__(384, 2) void k1t2(
    const float* __restrict__ x, const unsigned short* __restrict__ ABsw,
    const unsigned short* __restrict__ Wsw, const float* __restrict__ bm,
    unsigned short* __restrict__ h_relu, float* __restrict__ stats1) {
  __shared__ unsigned short xraw[80 * XRS];       // 16,640 B; rows r=(tt-t+1)*25+v, 75..79 zero
  __shared__ unsigned short tmp2[6][16 * T2S];    // 19,968 B [wave][o16][u']
  __shared__ float st1s[96], st2s[96];            //     768 B  (total 37,376 B)
  const int tid = threadIdx.x;
  const int n = blockIdx.x >> 7, t = blockIdx.x & 127;
  const int wave = tid >> 6, lane = tid & 63;
  const int l15 = lane & 15, quad = lane >> 4, q8 = quad * 8;

  // stage raw x slice: tt = t-1 .. t+1 (75 rows), zero-pad rows to 80
  for (int idx = tid; idx < 96 * 80; idx += 384) {
    int c = idx / 80, r = idx - c * 80;
    float v = 0.f;
    if (r < 75) {
      int tt = t - 1 + r / 25, vv = r % 25;
      if (tt >= 0 && tt < TB) v = x[((n * CB + c) * TB + tt) * VB + vv];
    }
    xraw[r * XRS + c] = f2bf(v);
  }
  // zero tmp2 cols u' in [80,96) (read by GEMM2 kk=2, never written by GEMM1;
  // ABsw cols u'>=75 are zero but uninitialized LDS could be NaN -> must zero)
  for (int idx = tid; idx < 6 * 256; idx += 384) {
    int w = idx >> 8, e = idx & 255;      // e = o*16 + (u'-80)
    tmp2[w][(e >> 4) * T2S + 80 + (e & 15)] = 0;
  }
  __syncthreads();

  const f32x4 zf = {0.f, 0.f, 0.f, 0.f};
  f32x4 acc2[5];   // [nt]: D[o][u], lane: u = nt*16+l15, o = 16*wave+4q+r
#pragma unroll
  for (int nt = 0; nt < 5; ++nt) acc2[nt] = zf;

  const unsigned short* Wbase = Wsw + wave * 1536 + lane * 8;   // + ps*9216 + kk*512
  const unsigned short* Bbase = ABsw + lane * 8;                // + ps*7680 + (nt*3+kk)*512
  unsigned short* tw = &tmp2[wave][l15 * T2S + quad * 4];       // b64 store base
  const unsigned short* tr = &tmp2[wave][l15 * T2S + q8];       // b128 read base

#pragma unroll
  for (int ps = 0; ps < 12; ++ps) {
    bf16x8 wa[3];
#pragma unroll
    for (int kk = 0; kk < 3; ++kk)
      wa[kk] = *reinterpret_cast<const bf16x8*>(Wbase + ps * 9216 + kk * 512);
    bf16x8 bf[15];
#pragma unroll
    for (int i = 0; i < 15; ++i)
      bf[i] = *reinterpret_cast<const bf16x8*>(Bbase + ps * 7680 + i * 512);

    // GEMM1' (SWAPPED operands): D'[u'][o16], u' = nt*16+4q+r, o16 = l15
    f32x4 acc1[5];
#pragma unroll
    for (int nt = 0; nt < 5; ++nt) acc1[nt] = zf;
#pragma unroll
    for (int kk = 0; kk < 3; ++kk)
#pragma unroll
      for (int nt = 0; nt < 5; ++nt) {
        bf16x8 a = *reinterpret_cast<const bf16x8*>(&xraw[(nt * 16 + l15) * XRS + kk * 32 + q8]);
        acc1[nt] = __builtin_amdgcn_mfma_f32_16x16x32_bf16(a, wa[kk], acc1[nt], 0, 0, 0);
      }
#pragma unroll
    for (int nt = 0; nt < 5; ++nt) {
      unsigned p01 = pack2bf(acc1[nt][0], acc1[nt][1]);
      unsigned p23 = pack2bf(acc1[nt][2], acc1[nt][3]);
      *reinterpret_cast<short4v*>(tw + nt * 16) =
          __builtin_bit_cast(short4v, (uint2v){p01, p23});
    }
    // RAW fence: tmp2 writes before GEMM2 reads (compiler ordering; HW in-order)
    asm volatile("" ::: "memory");
    __builtin_amdgcn_sched_barrier(0);

    // GEMM2 (original orientation): D[o][u] += tmp[o][u'] AB[u][u']
#pragma unroll
    for (int kk = 0; kk < 3; ++kk) {
      bf16x8 a0 = *reinterpret_cast<const bf16x8*>(tr + kk * 32);
#pragma unroll
      for (int nt = 0; nt < 5; ++nt)
        acc2[nt] = __builtin_amdgcn_mfma_f32_16x16x32_bf16(a0, bf[nt * 3 + kk], acc2[nt], 0, 0, 0);
    }
    // WAR fence: next ps's writes must not hoist above these reads
    asm volatile("" ::: "memory");
    __builtin_amdgcn_sched_barrier(0);
  }

  // epilogue: o = 16*wave+4q+r rows in regs, u = nt*16+l15.
  // HR layout = hnb layout: [n][t][vv][i*3+w], slice 7200 shorts per t.
  const int orow = wave * 16 + quad * 4;
  float s1[4] = {0.f, 0.f, 0.f, 0.f}, s2[4] = {0.f, 0.f, 0.f, 0.f};
  unsigned short* hp = h_relu + (unsigned)(n * TB + t) * 7200;
#pragma unroll
  for (int r = 0; r < 4; ++r) {
    const int o = orow + r;
    const float bias = bm[o];
#pragma unroll
    for (int nt = 0; nt < 5; ++nt) {
      int u = nt * 16 + l15;
      if (u < VLB) {
        float v = acc2[nt][r] + bias;
        v = v > 0.f ? v : 0.f;
        int w = u / 25, vv = u - w * 25;
        hp[vv * 288 + o * 3 + w] = f2bf(v);
        s1[r] += v;
        s2[r] += v * v;
      }
    }
  }
#pragma unroll
  for (int off = 1; off < 16; off <<= 1) {
#pragma unroll
    for (int r = 0; r < 4; ++r) {
      s1[r] += __shfl_xor(s1[r], off, 64);
      s2[r] += __shfl_xor(s2[r], off, 64);
    }
  }
  if (l15 == 0) {
#pragma unroll
    for (int r = 0; r < 4; ++r) { st1s[orow + r] = s1[r]; st2s[orow + r] = s2[r]; }
  }
  __syncthreads();
  if (tid < 96) {
    atomicAdd(&stats1[tid], st1s[tid]);
    atomicAdd(&stats1[96 + tid], st2s[tid]);
  }
}

// ---------------- K3: BN1-finalize + relu + out_conv (MFMA, 2 t/blk) --------
// grid = N*T/2 = 512 blocks. HR is already in hnb layout: staging is a linear
// b128-load -> BN+relu -> b128 LDS-write copy (no scatter).
__global__ __launch_bounds__(384) void k3n(
    const unsigned short* __restrict__ h_relu, const float* __restrict__ stats1,
    const float* __restrict__ g1, const float* __restrict__ bt1,
    const unsigned short* __restrict__ Wosw, const float* __restrict__ bo,
    float* __restrict__ out_pre) {
  __shared__ unsigned short hnb[2][32 * HBS];
  __shared__ float a1s[96], b1s[96];
  const int tid = threadIdx.x;
  const int n = blockIdx.x >> 6, t0 = (blockIdx.x & 63) * 2;

  if (tid < 96) {
    const float inv = 1.f / (8.f * 128.f * 75.f);
    float m = stats1[tid] * inv;
    float var = stats1[96 + tid] * inv - m * m;
    float a = g1[tid] * rsqrtf(var + EPSB);
    a1s[tid] = a;
    b1s[tid] = bt1[tid] - m * a;
  }
  for (int idx = tid; idx < 2 * 7 * HBS; idx += 384) {
    int d = idx / (7 * HBS), rm = idx % (7 * HBS);
    hnb[d][25 * HBS + rm] = 0;
  }
  __syncthreads();

  // linear staging: 14400 contiguous shorts; 288 % 8 == 0 so a b128 group
  // never straddles an hnb row; (vv*HBS + c)*2 is 16B-aligned (HBS=296=37*8).
  const unsigned short* hp = h_relu + (unsigned)(n * TB + t0) * 7200;
  for (int i8 = tid; i8 < 1800; i8 += 384) {
    bf16x8 v = *reinterpret_cast<const bf16x8*>(hp + i8 * 8);
    int e = i8 * 8;
    int d = e / 7200;
    int er = e - d * 7200;
    int vv = er / 288, c = er - vv * 288;
    float f[8];
#pragma unroll
    for (int j = 0; j < 8; ++j) {
      int ic = (c + j) / 3;
      float val = a1s[ic] * bf2f((unsigned short)v[j]) + b1s[ic];
      f[j] = val > 0.f ? val : 0.f;
    }
    unsigned dw0 = pack2bf(f[0], f[1]);
    unsigned dw1 = pack2bf(f[2], f[3]);
    unsigned dw2 = pack2bf(f[4], f[5]);
    unsigned dw3 = pack2bf(f[6], f[7]);
    *reinterpret_cast<uint4v*>(&hnb[d][vv * HBS + c]) = (uint4v){dw0, dw1, dw2, dw3};
  }
  __syncthreads();

  const int wave = tid >> 6, lane = tid & 63;
  const int l15 = lane & 15, quad = lane >> 4, q8 = quad * 8;
  const f32x4 zf = {0.f, 0.f, 0.f, 0.f};
  f32x4 acc[2][2] = {{zf, zf}, {zf, zf}};
  const unsigned short* Apw = Wosw + wave * 4608 + lane * 8;
#pragma unroll
  for (int kk = 0; kk < 9; ++kk) {
    bf16x8 a = *reinterpret_cast<const bf16x8*>(Apw + kk * 512);
#pragma unroll
    for (int d = 0; d < 2; ++d) {
      bf16x8 b0 = *reinterpret_cast<const bf16x8*>(&hnb[d][l15 * HBS + kk * 32 + q8]);
      bf16x8 b1 = *reinterpret_cast<const bf16x8*>(&hnb[d][(16 + l15) * HBS + kk * 32 + q8]);
      acc[d][0] = __builtin_amdgcn_mfma_f32_16x16x32_bf16(a, b0, acc[d][0], 0, 0, 0);
      acc[d][1] = __builtin_amdgcn_mfma_f32_16x16x32_bf16(a, b1, acc[d][1], 0, 0, 0);
    }
  }

  const int orow = wave * 16 + quad * 4;
#pragma unroll
  for (int d = 0; d < 2; ++d) {
#pragma unroll
    for (int nt = 0; nt < 2; ++nt) {
      int v = nt * 16 + l15;
      if (v < VB) {
#pragma unroll
        for (int r = 0; r < 4; ++r) {
          const int o = orow + r;
          out_pre[((n * CB + o) * TB + t0 + d) * VB + v] = acc[d][nt][r] + bo[o];
        }
      }
    }
  }
}

// ---------------- K4: BN2 stats (coalesced float4 reduction) ----------------
__global__ __launch_bounds__(256) void k4_stats(
    const float* __restrict__ out_pre, float* __restrict__ stats2) {
  __shared__ float ws1[4], ws2[4];
  const int tid = threadIdx.x;
  const int o = blockIdx.x % CB, p = blockIdx.x / CB;
  float s1 = 0.f, s2 = 0.f;
#pragma unroll
  for (int k = 0; k < 2; ++k) {
    const int n = 2 * p + k;
    const f32x4* base = reinterpret_cast<const f32x4*>(out_pre + (n * CB + o) * (TB * VB));
    for (int idx = tid; idx < TB * VB / 4; idx += 256) {
      f32x4 v = base[idx];
#pragma unroll
      for (int j = 0; j < 4; ++j) { s1 += v[j]; s2 += v[j] * v[j]; }
    }
  }
#pragma unroll
  for (int off = 1; off < 64; off <<= 1) {
    s1 += __shfl_xor(s1, off, 64);
    s2 += __shfl_xor(s2, off, 64);
  }
  const int wave = tid >> 6;
  if ((tid & 63) == 0) { ws1[wave] = s1; ws2[wave] = s2; }
  __syncthreads();
  if (tid == 0) {
    float r1 = ws1[0] + ws1[1] + ws1[2] + ws1[3];
    float r2 = ws2[0] + ws2[1] + ws2[2] + ws2[3];
    atomicAdd(&stats2[o], r1);
    atomicAdd(&stats2[96 + o], r2);
  }
}

// ---------------- K5: BN2 finalize (float4 elementwise) ----------------
__global__ __launch_bounds__(256) void k5_bn2(
    const float* __restrict__ out_pre, const float* __restrict__ stats2,
    const float* __restrict__ g2, const float* __restrict__ bt2,
    float* __restrict__ out) {
  int idx = blockIdx.x * 256 + threadIdx.x;
  if (idx >= NB * CB * TB * VB / 4) return;
  int o = (idx / (TB * VB / 4)) % CB;
  const float inv = 1.f / (8.f * 128.f * 25.f);
  float m = stats2[o] * inv;
  float var = stats2[96 + o] * inv - m * m;
  float a = g2[o] * rsqrtf(var + EPSB);
  float b = bt2[o] - m * a;
  f32x4 vin = reinterpret_cast<const f32x4*>(out_pre)[idx];
  f32x4 vo;
#pragma unroll
  for (int j = 0; j < 4; ++j) vo[j] = a * vin[j] + b;
  reinterpret_cast<f32x4*>(out)[idx] = vo;
}

extern "C" void kernel_launch(void* const* d_in, const int* in_sizes, int n_in,
                              void* d_out, int out_size, void* d_ws, size_t ws_size,
                              hipStream_t stream) {
  const float* x   = (const float*)d_in[0];
  const float* As  = (const float*)d_in[1];
  const float* Bs  = (const float*)d_in[2];
  const float* Ar  = (const float*)d_in[3];
  const float* Wm  = (const float*)d_in[4];
  const float* bm  = (const float*)d_in[5];
  const float* g1  = (const float*)d_in[6];
  const float* bt1 = (const float*)d_in[7];
  const float* Wo  = (const float*)d_in[8];
  const float* bo  = (const float*)d_in[9];
  const float* g2  = (const float*)d_in[10];
  const float* bt2 = (const float*)d_in[11];
  float* out = (float*)d_out;

  char* base = (char*)d_ws;
  unsigned short* HR   = (unsigned short*)base;                  // 14,745,600 B
  float* out_pre       = (float*)(base + 14745600);              //  9,830,400 B
  unsigned short* ABsw = (unsigned short*)(base + 24576000);     //    184,320 B
  unsigned short* Wsw  = (unsigned short*)(base + 24760320);     //    221,184 B
  unsigned short* Wosw = (unsigned short*)(base + 24981504);     //     55,296 B
  float* stats         = (float*)(base + 25036800);              //      1,536 B
  float* stats1 = stats, *stats2 = stats + 192;

  k0_init<<<432, 256, 0, stream>>>(As, Bs, Ar, Wm, Wo, ABsw, Wsw, Wosw, stats);
  k1t2<<<NB * TB, 384, 0, stream>>>(x, ABsw, Wsw, bm, HR, stats1);
  k3n<<<NB * TB / 2, 384, 0, stream>>>(HR, stats1, g1, bt1, Wosw, bo, out_pre);
  k4_stats<<<CB * 4, 256, 0, stream>>>(out_pre, stats2);
  k5_bn2<<<(NB * CB * TB * VB / 4 + 255) / 256, 256, 0, stream>>>(out_pre, stats2, g2, bt2, out);
}

// Round 12
// 175.124 us; speedup vs baseline: 1.5359x; 1.1348x over previous
//
#include <hip/hip_runtime.h>

// MS-G3D block. bf16-MFMA k1, t-chunk=2, dt SPLIT ACROSS WAVES (12 waves).
// Empirical law from 12 rounds: 384-thread blocks co-reside only ~1/CU
// (occupancy ~16% at ANY grid/LDS); the ONLY multi-block residency observed
// was round-10's 768-thread block (54%). Round 10 was poisoned solely by
// __launch_bounds__(768,6) -> allocator picked VGPR 40 + 290MB scratch.
// This rev = round-10 kernel VERBATIM (it passed correctness) with
// __launch_bounds__(768) only (no min-waves arg; VGPR cap 256, natural ~80).
// LDS 64,768B -> 2 blocks/CU = 24 waves/CU on the proven-resident shape.
// Packing stays manual f2bf|f2bf<<16 (cvt_pk operand order = rounds 5-7 bug).
// N=8, C=96, T=128, V=25, WIN=3, VL=75, NS=6.

#define NB 8
#define CB 96
#define TB 128
#define VB 25
#define VLB 75
#define EPSB 1e-5f
#define XRS 104   // xraw row stride (shorts)
#define T2S 104   // tmp2 row stride (shorts)
#define HBS 296   // hnb row stride (shorts)

typedef __attribute__((ext_vector_type(8))) short bf16x8;
typedef __attribute__((ext_vector_type(4))) short short4v;
typedef __attribute__((ext_vector_type(4))) float f32x4;
typedef __attribute__((ext_vector_type(2))) unsigned int uint2v;
typedef __attribute__((ext_vector_type(4))) unsigned int uint4v;

__device__ inline unsigned short f2bf(float f) {
  unsigned int u = __float_as_uint(f);
  u = (u + 0x7FFFu + ((u >> 16) & 1u)) >> 16;
  return (unsigned short)u;
}
__device__ inline float bf2f(unsigned short u) {
  return __uint_as_float(((unsigned int)u) << 16);
}
__device__ inline unsigned pack2bf(float lo, float hi) {
  return (unsigned)f2bf(lo) | ((unsigned)f2bf(hi) << 16);
}

// ---------------- K0: build fragment-swizzled bf16 weights; zero stats -------
// Wsw  [ps][wo][kk][lane][j] : W_ps[o=wo*16+(l&15)][c=kk*32+(l>>4)*8+j]
// ABsw [ps][nt][kk][lane][j] : AB_ps[u=nt*16+(l&15)][u'=kk*32+(l>>4)*8+j]
// Wosw [wv][kk][lane][j]     : Wo[o=wv*16+(l&15)][k=kk*32+(l>>4)*8+j]
__global__ __launch_bounds__(256) void k0_init(
    const float* __restrict__ As, const float* __restrict__ Bs,
    const float* __restrict__ Ar, const float* __restrict__ Wm,
    const float* __restrict__ Wo,
    unsigned short* __restrict__ ABsw, unsigned short* __restrict__ Wsw,
    unsigned short* __restrict__ Wosw, float* __restrict__ stats) {
  int i = blockIdx.x * 256 + threadIdx.x;
  if (i < 110592) {                     // Wsw: 12*6*3*512
    int ps = i / 9216, r = i % 9216;
    int wv = r / 1536, r2 = r % 1536;
    int kk = r2 / 512, r3 = r2 % 512;
    int lane = r3 / 8, j = r3 % 8;
    int o = wv * 16 + (lane & 15);
    int c = kk * 32 + (lane >> 4) * 8 + j;
    Wsw[i] = f2bf(Wm[o * 1152 + ps * 96 + c]);
  }
  if (i < 92160) {                      // ABsw: 12*5*3*512
    int ps = i / 7680, r = i % 7680;
    int nt = r / 1536, r2 = r % 1536;
    int kk = r2 / 512, r3 = r2 % 512;
    int lane = r3 / 8, j = r3 % 8;
    int u = nt * 16 + (lane & 15);
    int up = kk * 32 + (lane >> 4) * 8 + j;
    float v = 0.f;
    if (u < 75 && up < 75) {
      int path = ps / 6, s = ps % 6;
      int idx = (s * 75 + u) * 75 + up;
      v = (path == 0 ? As[idx] : Bs[idx]) + Ar[idx];
    }
    ABsw[i] = f2bf(v);
  }
  if (i < 27648) {                      // Wosw: 6*9*512
    int wv = i / 4608, r = i % 4608;
    int kk = r / 512, r3 = r % 512;
    int lane = r3 / 8, j = r3 % 8;
    int o = wv * 16 + (lane & 15);
    int k = kk * 32 + (lane >> 4) * 8 + j;
    Wosw[i] = f2bf(Wo[o * 288 + k]);
  }
  if (i < 384) stats[i] = 0.f;
}

// ---------------- K1: t2 fused (MLP -> agg) x12 MFMA, 12 waves ---------------
// grid = N*T/2 = 512 blocks, 768 threads. wave = wo*2+dt: wo owns o-rows
// [16wo,16wo+16), dt owns t = t0+dt. Each wave: per ps, GEMM1'(one dt) ->
// pack -> ds_write_b64 x5 -> fence -> GEMM2 -> fence. Private tmp2[wave].
__global__ __launch_bounds__(768) void k1t2(
    const float* __restrict__ x, const unsigned short* __restrict__ ABsw,
    const unsigned short* __restrict__ Wsw, const float* __restrict__ bm,
    unsigned short* __restrict__ h_relu, float* __restrict__ stats1) {
  __shared__ unsigned short xraw[112 * XRS];      // 23,296 B
  __shared__ unsigned short tmp2[12][16 * T2S];   // 39,936 B [wave][o16][u']
  __shared__ float st1s[2][96], st2s[2][96];      //  1,536 B  (total 64,768 B)
  const int tid = threadIdx.x;
  const int n = blockIdx.x >> 6, t0 = (blockIdx.x & 63) * 2;
  const int wave = tid >> 6, lane = tid & 63;
  const int wo = wave >> 1, dt = wave & 1;
  const int l15 = lane & 15, quad = lane >> 4, q8 = quad * 8;

  // stage raw x slice: tt = t0-1 .. t0+2 (100 rows), zero-pad rows to 112
  for (int idx = tid; idx < 96 * 112; idx += 768) {
    int c = idx / 112, r = idx - c * 112;
    float v = 0.f;
    if (r < 100) {
      int tt = t0 - 1 + r / 25, vv = r % 25;
      if (tt >= 0 && tt < TB) v = x[((n * CB + c) * TB + tt) * VB + vv];
    }
    xraw[r * XRS + c] = f2bf(v);
  }
  // zero tmp2 cols u' in [80,96) (read by GEMM2 kk=2, never written by GEMM1;
  // ABsw cols u'>=75 are zero but uninitialized LDS could be NaN -> must zero)
  for (int idx = tid; idx < 12 * 256; idx += 768) {
    int w = idx >> 8, e = idx & 255;      // e = o*16 + (u'-80)
    tmp2[w][(e >> 4) * T2S + 80 + (e & 15)] = 0;
  }
  __syncthreads();

  const f32x4 zf = {0.f, 0.f, 0.f, 0.f};
  f32x4 acc2[5];   // [nt]: D[o][u], lane: u = nt*16+l15, o = 16wo+4q+r
#pragma unroll
  for (int nt = 0; nt < 5; ++nt) acc2[nt] = zf;

  const unsigned short* Wbase = Wsw + wo * 1536 + lane * 8;   // + ps*9216 + kk*512
  const unsigned short* Bbase = ABsw + lane * 8;              // + ps*7680 + (nt*3+kk)*512
  unsigned short* tw = &tmp2[wave][l15 * T2S + quad * 4];     // b64 store base
  const unsigned short* tr = &tmp2[wave][l15 * T2S + q8];     // b128 read base
  const int xoff = dt * 25;   // xraw row offset for this wave's t

#pragma unroll
  for (int ps = 0; ps < 12; ++ps) {
    bf16x8 wa[3];
#pragma unroll
    for (int kk = 0; kk < 3; ++kk)
      wa[kk] = *reinterpret_cast<const bf16x8*>(Wbase + ps * 9216 + kk * 512);
    bf16x8 bf[15];
#pragma unroll
    for (int i = 0; i < 15; ++i)
      bf[i] = *reinterpret_cast<const bf16x8*>(Bbase + ps * 7680 + i * 512);

    // GEMM1' (SWAPPED operands): D'[u'][o16], u' = nt*16+4q+r, o16 = l15
    f32x4 acc1[5];
#pragma unroll
    for (int nt = 0; nt < 5; ++nt) acc1[nt] = zf;
#pragma unroll
    for (int kk = 0; kk < 3; ++kk)
#pragma unroll
      for (int nt = 0; nt < 5; ++nt) {
        bf16x8 a = *reinterpret_cast<const bf16x8*>(&xraw[(xoff + nt * 16 + l15) * XRS + kk * 32 + q8]);
        acc1[nt] = __builtin_amdgcn_mfma_f32_16x16x32_bf16(a, wa[kk], acc1[nt], 0, 0, 0);
      }
#pragma unroll
    for (int nt = 0; nt < 5; ++nt) {
      unsigned p01 = pack2bf(acc1[nt][0], acc1[nt][1]);
      unsigned p23 = pack2bf(acc1[nt][2], acc1[nt][3]);
      *reinterpret_cast<short4v*>(tw + nt * 16) =
          __builtin_bit_cast(short4v, (uint2v){p01, p23});
    }
    // RAW fence: tmp2 writes before GEMM2 reads (compiler ordering; HW in-order)
    asm volatile("" ::: "memory");
    __builtin_amdgcn_sched_barrier(0);

    // GEMM2 (original orientation): D[o][u] += tmp[o][u'] AB[u][u']
#pragma unroll
    for (int kk = 0; kk < 3; ++kk) {
      bf16x8 a0 = *reinterpret_cast<const bf16x8*>(tr + kk * 32);
#pragma unroll
      for (int nt = 0; nt < 5; ++nt)
        acc2[nt] = __builtin_amdgcn_mfma_f32_16x16x32_bf16(a0, bf[nt * 3 + kk], acc2[nt], 0, 0, 0);
    }
    // WAR fence: next ps's writes must not hoist above these reads
    asm volatile("" ::: "memory");
    __builtin_amdgcn_sched_barrier(0);
  }

  // epilogue: o = 16wo+4q+r rows in regs, u = nt*16+l15, t = t0+dt.
  // HR layout = hnb layout: [n][t][vv][i*3+w], slice 7200 shorts per t.
  const int orow = wo * 16 + quad * 4;
  float s1[4] = {0.f, 0.f, 0.f, 0.f}, s2[4] = {0.f, 0.f, 0.f, 0.f};
  unsigned short* hp = h_relu + (unsigned)(n * TB + t0) * 7200 + dt * 7200;
#pragma unroll
  for (int r = 0; r < 4; ++r) {
    const int o = orow + r;
    const float bias = bm[o];
#pragma unroll
    for (int nt = 0; nt < 5; ++nt) {
      int u = nt * 16 + l15;
      if (u < VLB) {
        float v = acc2[nt][r] + bias;
        v = v > 0.f ? v : 0.f;
        int w = u / 25, vv = u - w * 25;
        hp[vv * 288 + o * 3 + w] = f2bf(v);
        s1[r] += v;
        s2[r] += v * v;
      }
    }
  }
#pragma unroll
  for (int off = 1; off < 16; off <<= 1) {
#pragma unroll
    for (int r = 0; r < 4; ++r) {
      s1[r] += __shfl_xor(s1[r], off, 64);
      s2[r] += __shfl_xor(s2[r], off, 64);
    }
  }
  if (l15 == 0) {
#pragma unroll
    for (int r = 0; r < 4; ++r) { st1s[dt][orow + r] = s1[r]; st2s[dt][orow + r] = s2[r]; }
  }
  __syncthreads();
  if (tid < 96) {
    atomicAdd(&stats1[tid], st1s[0][tid] + st1s[1][tid]);
    atomicAdd(&stats1[96 + tid], st2s[0][tid] + st2s[1][tid]);
  }
}

// ---------------- K3: BN1-finalize + relu + out_conv (MFMA, 2 t/blk) --------
// grid = N*T/2 = 512 blocks. HR is already in hnb layout: staging is a linear
// b128-load -> BN+relu -> b128 LDS-write copy (no scatter).
__global__ __launch_bounds__(384) void k3n(
    const unsigned short* __restrict__ h_relu, const float* __restrict__ stats1,
    const float* __restrict__ g1, const float* __restrict__ bt1,
    const unsigned short* __restrict__ Wosw, const float* __restrict__ bo,
    float* __restrict__ out_pre) {
  __shared__ unsigned short hnb[2][32 * HBS];
  __shared__ float a1s[96], b1s[96];
  const int tid = threadIdx.x;
  const int n = blockIdx.x >> 6, t0 = (blockIdx.x & 63) * 2;

  if (tid < 96) {
    const float inv = 1.f / (8.f * 128.f * 75.f);
    float m = stats1[tid] * inv;
    float var = stats1[96 + tid] * inv - m * m;
    float a = g1[tid] * rsqrtf(var + EPSB);
    a1s[tid] = a;
    b1s[tid] = bt1[tid] - m * a;
  }
  for (int idx = tid; idx < 2 * 7 * HBS; idx += 384) {
    int d = idx / (7 * HBS), rm = idx % (7 * HBS);
    hnb[d][25 * HBS + rm] = 0;
  }
  __syncthreads();

  // linear staging: 14400 contiguous shorts; 288 % 8 == 0 so a b128 group
  // never straddles an hnb row; (vv*HBS + c)*2 is 16B-aligned (HBS=296=37*8).
  const unsigned short* hp = h_relu + (unsigned)(n * TB + t0) * 7200;
  for (int i8 = tid; i8 < 1800; i8 += 384) {
    bf16x8 v = *reinterpret_cast<const bf16x8*>(hp + i8 * 8);
    int e = i8 * 8;
    int d = e / 7200;
    int er = e - d * 7200;
    int vv = er / 288, c = er - vv * 288;
    float f[8];
#pragma unroll
    for (int j = 0; j < 8; ++j) {
      int ic = (c + j) / 3;
      float val = a1s[ic] * bf2f((unsigned short)v[j]) + b1s[ic];
      f[j] = val > 0.f ? val : 0.f;
    }
    unsigned dw0 = pack2bf(f[0], f[1]);
    unsigned dw1 = pack2bf(f[2], f[3]);
    unsigned dw2 = pack2bf(f[4], f[5]);
    unsigned dw3 = pack2bf(f[6], f[7]);
    *reinterpret_cast<uint4v*>(&hnb[d][vv * HBS + c]) = (uint4v){dw0, dw1, dw2, dw3};
  }
  __syncthreads();

  const int wave = tid >> 6, lane = tid & 63;
  const int l15 = lane & 15, quad = lane >> 4, q8 = quad * 8;
  const f32x4 zf = {0.f, 0.f, 0.f, 0.f};
  f32x4 acc[2][2] = {{zf, zf}, {zf, zf}};
  const unsigned short* Apw = Wosw + wave * 4608 + lane * 8;
#pragma unroll
  for (int kk = 0; kk < 9; ++kk) {
    bf16x8 a = *reinterpret_cast<const bf16x8*>(Apw + kk * 512);
#pragma unroll
    for (int d = 0; d < 2; ++d) {
      bf16x8 b0 = *reinterpret_cast<const bf16x8*>(&hnb[d][l15 * HBS + kk * 32 + q8]);
      bf16x8 b1 = *reinterpret_cast<const bf16x8*>(&hnb[d][(16 + l15) * HBS + kk * 32 + q8]);
      acc[d][0] = __builtin_amdgcn_mfma_f32_16x16x32_bf16(a, b0, acc[d][0], 0, 0, 0);
      acc[d][1] = __builtin_amdgcn_mfma_f32_16x16x32_bf16(a, b1, acc[d][1], 0, 0, 0);
    }
  }

  const int orow = wave * 16 + quad * 4;
#pragma unroll
  for (int d = 0; d < 2; ++d) {
#pragma unroll
    for (int nt = 0; nt < 2; ++nt) {
      int v = nt * 16 + l15;
      if (v < VB) {
#pragma unroll
        for (int r = 0; r < 4; ++r) {
          const int o = orow + r;
          out_pre[((n * CB + o) * TB + t0 + d) * VB + v] = acc[d][nt][r] + bo[o];
        }
      }
    }
  }
}

// ---------------- K4: BN2 stats (coalesced float4 reduction) ----------------
__global__ __launch_bounds__(256) void k4_stats(
    const float* __restrict__ out_pre, float* __restrict__ stats2) {
  __shared__ float ws1[4], ws2[4];
  const int tid = threadIdx.x;
  const int o = blockIdx.x % CB, p = blockIdx.x / CB;
  float s1 = 0.f, s2 = 0.f;
#pragma unroll
  for (int k = 0; k < 2; ++k) {
    const int n = 2 * p + k;
    const f32x4* base = reinterpret_cast<const f32x4*>(out_pre + (n * CB + o) * (TB * VB));
    for (int idx = tid; idx < TB * VB / 4; idx += 256) {
      f32x4 v = base[idx];
#pragma unroll
      for (int j = 0; j < 4; ++j) { s1 += v[j]; s2 += v[j] * v[j]; }
    }
  }
#pragma unroll
  for (int off = 1; off < 64; off <<= 1) {
    s1 += __shfl_xor(s1, off, 64);
    s2 += __shfl_xor(s2, off, 64);
  }
  const int wave = tid >> 6;
  if ((tid & 63) == 0) { ws1[wave] = s1; ws2[wave] = s2; }
  __syncthreads();
  if (tid == 0) {
    float r1 = ws1[0] + ws1[1] + ws1[2] + ws1[3];
    float r2 = ws2[0] + ws2[1] + ws2[2] + ws2[3];
    atomicAdd(&stats2[o], r1);
    atomicAdd(&stats2[96 + o], r2);
  }
}

// ---------------- K5: BN2 finalize (float4 elementwise) ----------------
__global__ __launch_bounds__(256) void k5_bn2(
    const float* __restrict__ out_pre, const float* __restrict__ stats2,
    const float* __restrict__ g2, const float* __restrict__ bt2,
    float* __restrict__ out) {
  int idx = blockIdx.x * 256 + threadIdx.x;
  if (idx >= NB * CB * TB * VB / 4) return;
  int o = (idx / (TB * VB / 4)) % CB;
  const float inv = 1.f / (8.f * 128.f * 25.f);
  float m = stats2[o] * inv;
  float var = stats2[96 + o] * inv - m * m;
  float a = g2[o] * rsqrtf(var + EPSB);
  float b = bt2[o] - m * a;
  f32x4 vin = reinterpret_cast<const f32x4*>(out_pre)[idx];
  f32x4 vo;
#pragma unroll
  for (int j = 0; j < 4; ++j) vo[j] = a * vin[j] + b;
  reinterpret_cast<f32x4*>(out)[idx] = vo;
}

extern "C" void kernel_launch(void* const* d_in, const int* in_sizes, int n_in,
                              void* d_out, int out_size, void* d_ws, size_t ws_size,
                              hipStream_t stream) {
  const float* x   = (const float*)d_in[0];
  const float* As  = (const float*)d_in[1];
  const float* Bs  = (const float*)d_in[2];
  const float* Ar  = (const float*)d_in[3];
  const float* Wm  = (const float*)d_in[4];
  const float* bm  = (const float*)d_in[5];
  const float* g1  = (const float*)d_in[6];
  const float* bt1 = (const float*)d_in[7];
  const float* Wo  = (const float*)d_in[8];
  const float* bo  = (const float*)d_in[9];
  const float* g2  = (const float*)d_in[10];
  const float* bt2 = (const float*)d_in[11];
  float* out = (float*)d_out;

  char* base = (char*)d_ws;
  unsigned short* HR   = (unsigned short*)base;                  // 14,745,600 B
  float* out_pre       = (float*)(base + 14745600);              //  9,830,400 B
  unsigned short* ABsw = (unsigned short*)(base + 24576000);     //    184,320 B
  unsigned short* Wsw  = (unsigned short*)(base + 24760320);     //    221,184 B
  unsigned short* Wosw = (unsigned short*)(base + 24981504);     //     55,296 B
  float* stats         = (float*)(base + 25036800);              //      1,536 B
  float* stats1 = stats, *stats2 = stats + 192;

  k0_init<<<432, 256, 0, stream>>>(As, Bs, Ar, Wm, Wo, ABsw, Wsw, Wosw, stats);
  k1t2<<<NB * TB / 2, 768, 0, stream>>>(x, ABsw, Wsw, bm, HR, stats1);
  k3n<<<NB * TB / 2, 384, 0, stream>>>(HR, stats1, g1, bt1, Wosw, bo, out_pre);
  k4_stats<<<CB * 4, 256, 0, stream>>>(out_pre, stats2);
  k5_bn2<<<(NB * CB * TB * VB / 4 + 255) / 256, 256, 0, stream>>>(out_pre, stats2, g2, bt2, out);
}

// Round 13
// 172.564 us; speedup vs baseline: 1.5587x; 1.0148x over previous
//
#include <hip/hip_runtime.h>

// MS-G3D block. bf16-MFMA k1 (round-12 form, 768thr, ~84us) + k3n ported to
// the proven 768-thread shape. Budget arithmetic: total 175 = k1 84 + ~91us
// tail; rooflines put k0/k4/k5 at ~7us -> k3n ~= 70-80us, latency-bound HBM
// staging at single-block-per-CU residency (the 13-round law: 384-thr blocks
// never co-reside; 768-thr blocks do). k3n: 12 waves = (wo,dt), each wave
// owns o-rows [16wo,16wo+16) of one t; staging strides 768; LDS 38.7KB ->
// 2 blocks/CU = 24 waves/CU. k1/k0/k4/k5 byte-identical to round 12.
// Packing stays manual f2bf|f2bf<<16 (cvt_pk operand order = rounds 5-7 bug).
// N=8, C=96, T=128, V=25, WIN=3, VL=75, NS=6.

#define NB 8
#define CB 96
#define TB 128
#define VB 25
#define VLB 75
#define EPSB 1e-5f
#define XRS 104   // xraw row stride (shorts)
#define T2S 104   // tmp2 row stride (shorts)
#define HBS 296   // hnb row stride (shorts)

typedef __attribute__((ext_vector_type(8))) short bf16x8;
typedef __attribute__((ext_vector_type(4))) short short4v;
typedef __attribute__((ext_vector_type(4))) float f32x4;
typedef __attribute__((ext_vector_type(2))) unsigned int uint2v;
typedef __attribute__((ext_vector_type(4))) unsigned int uint4v;

__device__ inline unsigned short f2bf(float f) {
  unsigned int u = __float_as_uint(f);
  u = (u + 0x7FFFu + ((u >> 16) & 1u)) >> 16;
  return (unsigned short)u;
}
__device__ inline float bf2f(unsigned short u) {
  return __uint_as_float(((unsigned int)u) << 16);
}
__device__ inline unsigned pack2bf(float lo, float hi) {
  return (unsigned)f2bf(lo) | ((unsigned)f2bf(hi) << 16);
}

// ---------------- K0: build fragment-swizzled bf16 weights; zero stats -------
// Wsw  [ps][wo][kk][lane][j] : W_ps[o=wo*16+(l&15)][c=kk*32+(l>>4)*8+j]
// ABsw [ps][nt][kk][lane][j] : AB_ps[u=nt*16+(l&15)][u'=kk*32+(l>>4)*8+j]
// Wosw [wv][kk][lane][j]     : Wo[o=wv*16+(l&15)][k=kk*32+(l>>4)*8+j]
__global__ __launch_bounds__(256) void k0_init(
    const float* __restrict__ As, const float* __restrict__ Bs,
    const float* __restrict__ Ar, const float* __restrict__ Wm,
    const float* __restrict__ Wo,
    unsigned short* __restrict__ ABsw, unsigned short* __restrict__ Wsw,
    unsigned short* __restrict__ Wosw, float* __restrict__ stats) {
  int i = blockIdx.x * 256 + threadIdx.x;
  if (i < 110592) {                     // Wsw: 12*6*3*512
    int ps = i / 9216, r = i % 9216;
    int wv = r / 1536, r2 = r % 1536;
    int kk = r2 / 512, r3 = r2 % 512;
    int lane = r3 / 8, j = r3 % 8;
    int o = wv * 16 + (lane & 15);
    int c = kk * 32 + (lane >> 4) * 8 + j;
    Wsw[i] = f2bf(Wm[o * 1152 + ps * 96 + c]);
  }
  if (i < 92160) {                      // ABsw: 12*5*3*512
    int ps = i / 7680, r = i % 7680;
    int nt = r / 1536, r2 = r % 1536;
    int kk = r2 / 512, r3 = r2 % 512;
    int lane = r3 / 8, j = r3 % 8;
    int u = nt * 16 + (lane & 15);
    int up = kk * 32 + (lane >> 4) * 8 + j;
    float v = 0.f;
    if (u < 75 && up < 75) {
      int path = ps / 6, s = ps % 6;
      int idx = (s * 75 + u) * 75 + up;
      v = (path == 0 ? As[idx] : Bs[idx]) + Ar[idx];
    }
    ABsw[i] = f2bf(v);
  }
  if (i < 27648) {                      // Wosw: 6*9*512
    int wv = i / 4608, r = i % 4608;
    int kk = r / 512, r3 = r % 512;
    int lane = r3 / 8, j = r3 % 8;
    int o = wv * 16 + (lane & 15);
    int k = kk * 32 + (lane >> 4) * 8 + j;
    Wosw[i] = f2bf(Wo[o * 288 + k]);
  }
  if (i < 384) stats[i] = 0.f;
}

// ---------------- K1: t2 fused (MLP -> agg) x12 MFMA, 12 waves ---------------
// grid = N*T/2 = 512 blocks, 768 threads. wave = wo*2+dt: wo owns o-rows
// [16wo,16wo+16), dt owns t = t0+dt. Each wave: per ps, GEMM1'(one dt) ->
// pack -> ds_write_b64 x5 -> fence -> GEMM2 -> fence. Private tmp2[wave].
__global__ __launch_bounds__(768) void k1t2(
    const float* __restrict__ x, const unsigned short* __restrict__ ABsw,
    const unsigned short* __restrict__ Wsw, const float* __restrict__ bm,
    unsigned short* __restrict__ h_relu, float* __restrict__ stats1) {
  __shared__ unsigned short xraw[112 * XRS];      // 23,296 B
  __shared__ unsigned short tmp2[12][16 * T2S];   // 39,936 B [wave][o16][u']
  __shared__ float st1s[2][96], st2s[2][96];      //  1,536 B  (total 64,768 B)
  const int tid = threadIdx.x;
  const int n = blockIdx.x >> 6, t0 = (blockIdx.x & 63) * 2;
  const int wave = tid >> 6, lane = tid & 63;
  const int wo = wave >> 1, dt = wave & 1;
  const int l15 = lane & 15, quad = lane >> 4, q8 = quad * 8;

  // stage raw x slice: tt = t0-1 .. t0+2 (100 rows), zero-pad rows to 112
  for (int idx = tid; idx < 96 * 112; idx += 768) {
    int c = idx / 112, r = idx - c * 112;
    float v = 0.f;
    if (r < 100) {
      int tt = t0 - 1 + r / 25, vv = r % 25;
      if (tt >= 0 && tt < TB) v = x[((n * CB + c) * TB + tt) * VB + vv];
    }
    xraw[r * XRS + c] = f2bf(v);
  }
  // zero tmp2 cols u' in [80,96) (read by GEMM2 kk=2, never written by GEMM1;
  // ABsw cols u'>=75 are zero but uninitialized LDS could be NaN -> must zero)
  for (int idx = tid; idx < 12 * 256; idx += 768) {
    int w = idx >> 8, e = idx & 255;      // e = o*16 + (u'-80)
    tmp2[w][(e >> 4) * T2S + 80 + (e & 15)] = 0;
  }
  __syncthreads();

  const f32x4 zf = {0.f, 0.f, 0.f, 0.f};
  f32x4 acc2[5];   // [nt]: D[o][u], lane: u = nt*16+l15, o = 16wo+4q+r
#pragma unroll
  for (int nt = 0; nt < 5; ++nt) acc2[nt] = zf;

  const unsigned short* Wbase = Wsw + wo * 1536 + lane * 8;   // + ps*9216 + kk*512
  const unsigned short* Bbase = ABsw + lane * 8;              // + ps*7680 + (nt*3+kk)*512
  unsigned short* tw = &tmp2[wave][l15 * T2S + quad * 4];     // b64 store base
  const unsigned short* tr = &tmp2[wave][l15 * T2S + q8];     // b128 read base
  const int xoff = dt * 25;   // xraw row offset for this wave's t

#pragma unroll
  for (int ps = 0; ps < 12; ++ps) {
    bf16x8 wa[3];
#pragma unroll
    for (int kk = 0; kk < 3; ++kk)
      wa[kk] = *reinterpret_cast<const bf16x8*>(Wbase + ps * 9216 + kk * 512);
    bf16x8 bf[15];
#pragma unroll
    for (int i = 0; i < 15; ++i)
      bf[i] = *reinterpret_cast<const bf16x8*>(Bbase + ps * 7680 + i * 512);

    // GEMM1' (SWAPPED operands): D'[u'][o16], u' = nt*16+4q+r, o16 = l15
    f32x4 acc1[5];
#pragma unroll
    for (int nt = 0; nt < 5; ++nt) acc1[nt] = zf;
#pragma unroll
    for (int kk = 0; kk < 3; ++kk)
#pragma unroll
      for (int nt = 0; nt < 5; ++nt) {
        bf16x8 a = *reinterpret_cast<const bf16x8*>(&xraw[(xoff + nt * 16 + l15) * XRS + kk * 32 + q8]);
        acc1[nt] = __builtin_amdgcn_mfma_f32_16x16x32_bf16(a, wa[kk], acc1[nt], 0, 0, 0);
      }
#pragma unroll
    for (int nt = 0; nt < 5; ++nt) {
      unsigned p01 = pack2bf(acc1[nt][0], acc1[nt][1]);
      unsigned p23 = pack2bf(acc1[nt][2], acc1[nt][3]);
      *reinterpret_cast<short4v*>(tw + nt * 16) =
          __builtin_bit_cast(short4v, (uint2v){p01, p23});
    }
    // RAW fence: tmp2 writes before GEMM2 reads (compiler ordering; HW in-order)
    asm volatile("" ::: "memory");
    __builtin_amdgcn_sched_barrier(0);

    // GEMM2 (original orientation): D[o][u] += tmp[o][u'] AB[u][u']
#pragma unroll
    for (int kk = 0; kk < 3; ++kk) {
      bf16x8 a0 = *reinterpret_cast<const bf16x8*>(tr + kk * 32);
#pragma unroll
      for (int nt = 0; nt < 5; ++nt)
        acc2[nt] = __builtin_amdgcn_mfma_f32_16x16x32_bf16(a0, bf[nt * 3 + kk], acc2[nt], 0, 0, 0);
    }
    // WAR fence: next ps's writes must not hoist above these reads
    asm volatile("" ::: "memory");
    __builtin_amdgcn_sched_barrier(0);
  }

  // epilogue: o = 16wo+4q+r rows in regs, u = nt*16+l15, t = t0+dt.
  // HR layout = hnb layout: [n][t][vv][i*3+w], slice 7200 shorts per t.
  const int orow = wo * 16 + quad * 4;
  float s1[4] = {0.f, 0.f, 0.f, 0.f}, s2[4] = {0.f, 0.f, 0.f, 0.f};
  unsigned short* hp = h_relu + (unsigned)(n * TB + t0) * 7200 + dt * 7200;
#pragma unroll
  for (int r = 0; r < 4; ++r) {
    const int o = orow + r;
    const float bias = bm[o];
#pragma unroll
    for (int nt = 0; nt < 5; ++nt) {
      int u = nt * 16 + l15;
      if (u < VLB) {
        float v = acc2[nt][r] + bias;
        v = v > 0.f ? v : 0.f;
        int w = u / 25, vv = u - w * 25;
        hp[vv * 288 + o * 3 + w] = f2bf(v);
        s1[r] += v;
        s2[r] += v * v;
      }
    }
  }
#pragma unroll
  for (int off = 1; off < 16; off <<= 1) {
#pragma unroll
    for (int r = 0; r < 4; ++r) {
      s1[r] += __shfl_xor(s1[r], off, 64);
      s2[r] += __shfl_xor(s2[r], off, 64);
    }
  }
  if (l15 == 0) {
#pragma unroll
    for (int r = 0; r < 4; ++r) { st1s[dt][orow + r] = s1[r]; st2s[dt][orow + r] = s2[r]; }
  }
  __syncthreads();
  if (tid < 96) {
    atomicAdd(&stats1[tid], st1s[0][tid] + st1s[1][tid]);
    atomicAdd(&stats1[96 + tid], st2s[0][tid] + st2s[1][tid]);
  }
}

// ---------------- K3: BN1-finalize + relu + out_conv (768 thr, 2 t/blk) -----
// grid = N*T/2 = 512 blocks, 768 threads (12 waves): wave = (wo, dt), wave
// owns o-rows [16wo,16wo+16) of t = t0+dt (18 MFMA, acc[2]). HR is in hnb
// layout: staging is a linear b128->math->b128 copy striding 768.
// LDS 38,656B -> 2 blocks/CU = 24 waves/CU (the 768-thr residency law).
__global__ __launch_bounds__(768) void k3n(
    const unsigned short* __restrict__ h_relu, const float* __restrict__ stats1,
    const float* __restrict__ g1, const float* __restrict__ bt1,
    const unsigned short* __restrict__ Wosw, const float* __restrict__ bo,
    float* __restrict__ out_pre) {
  __shared__ unsigned short hnb[2][32 * HBS];
  __shared__ float a1s[96], b1s[96];
  const int tid = threadIdx.x;
  const int n = blockIdx.x >> 6, t0 = (blockIdx.x & 63) * 2;

  if (tid < 96) {
    const float inv = 1.f / (8.f * 128.f * 75.f);
    float m = stats1[tid] * inv;
    float var = stats1[96 + tid] * inv - m * m;
    float a = g1[tid] * rsqrtf(var + EPSB);
    a1s[tid] = a;
    b1s[tid] = bt1[tid] - m * a;
  }
  for (int idx = tid; idx < 2 * 7 * HBS; idx += 768) {
    int d = idx / (7 * HBS), rm = idx % (7 * HBS);
    hnb[d][25 * HBS + rm] = 0;
  }
  __syncthreads();

  // linear staging: 14400 contiguous shorts; 288 % 8 == 0 so a b128 group
  // never straddles an hnb row; (vv*HBS + c)*2 is 16B-aligned (HBS=296=37*8).
  const unsigned short* hp = h_relu + (unsigned)(n * TB + t0) * 7200;
  for (int i8 = tid; i8 < 1800; i8 += 768) {
    bf16x8 v = *reinterpret_cast<const bf16x8*>(hp + i8 * 8);
    int e = i8 * 8;
    int d = e / 7200;
    int er = e - d * 7200;
    int vv = er / 288, c = er - vv * 288;
    float f[8];
#pragma unroll
    for (int j = 0; j < 8; ++j) {
      int ic = (c + j) / 3;
      float val = a1s[ic] * bf2f((unsigned short)v[j]) + b1s[ic];
      f[j] = val > 0.f ? val : 0.f;
    }
    unsigned dw0 = pack2bf(f[0], f[1]);
    unsigned dw1 = pack2bf(f[2], f[3]);
    unsigned dw2 = pack2bf(f[4], f[5]);
    unsigned dw3 = pack2bf(f[6], f[7]);
    *reinterpret_cast<uint4v*>(&hnb[d][vv * HBS + c]) = (uint4v){dw0, dw1, dw2, dw3};
  }
  __syncthreads();

  const int wave = tid >> 6, lane = tid & 63;
  const int wo = wave >> 1, dt = wave & 1;
  const int l15 = lane & 15, quad = lane >> 4, q8 = quad * 8;
  const f32x4 zf = {0.f, 0.f, 0.f, 0.f};
  f32x4 acc[2] = {zf, zf};
  const unsigned short* Apw = Wosw + wo * 4608 + lane * 8;
#pragma unroll
  for (int kk = 0; kk < 9; ++kk) {
    bf16x8 a = *reinterpret_cast<const bf16x8*>(Apw + kk * 512);
    bf16x8 b0 = *reinterpret_cast<const bf16x8*>(&hnb[dt][l15 * HBS + kk * 32 + q8]);
    bf16x8 b1 = *reinterpret_cast<const bf16x8*>(&hnb[dt][(16 + l15) * HBS + kk * 32 + q8]);
    acc[0] = __builtin_amdgcn_mfma_f32_16x16x32_bf16(a, b0, acc[0], 0, 0, 0);
    acc[1] = __builtin_amdgcn_mfma_f32_16x16x32_bf16(a, b1, acc[1], 0, 0, 0);
  }

  const int orow = wo * 16 + quad * 4;
#pragma unroll
  for (int nt = 0; nt < 2; ++nt) {
    int v = nt * 16 + l15;
    if (v < VB) {
#pragma unroll
      for (int r = 0; r < 4; ++r) {
        const int o = orow + r;
        out_pre[((n * CB + o) * TB + t0 + dt) * VB + v] = acc[nt][r] + bo[o];
      }
    }
  }
}

// ---------------- K4: BN2 stats (coalesced float4 reduction) ----------------
__global__ __launch_bounds__(256) void k4_stats(
    const float* __restrict__ out_pre, float* __restrict__ stats2) {
  __shared__ float ws1[4], ws2[4];
  const int tid = threadIdx.x;
  const int o = blockIdx.x % CB, p = blockIdx.x / CB;
  float s1 = 0.f, s2 = 0.f;
#pragma unroll
  for (int k = 0; k < 2; ++k) {
    const int n = 2 * p + k;
    const f32x4* base = reinterpret_cast<const f32x4*>(out_pre + (n * CB + o) * (TB * VB));
    for (int idx = tid; idx < TB * VB / 4; idx += 256) {
      f32x4 v = base[idx];
#pragma unroll
      for (int j = 0; j < 4; ++j) { s1 += v[j]; s2 += v[j] * v[j]; }
    }
  }
#pragma unroll
  for (int off = 1; off < 64; off <<= 1) {
    s1 += __shfl_xor(s1, off, 64);
    s2 += __shfl_xor(s2, off, 64);
  }
  const int wave = tid >> 6;
  if ((tid & 63) == 0) { ws1[wave] = s1; ws2[wave] = s2; }
  __syncthreads();
  if (tid == 0) {
    float r1 = ws1[0] + ws1[1] + ws1[2] + ws1[3];
    float r2 = ws2[0] + ws2[1] + ws2[2] + ws2[3];
    atomicAdd(&stats2[o], r1);
    atomicAdd(&stats2[96 + o], r2);
  }
}

// ---------------- K5: BN2 finalize (float4 elementwise) ----------------
__global__ __launch_bounds__(256) void k5_bn2(
    const float* __restrict__ out_pre, const float* __restrict__ stats2,
    const float* __restrict__ g2, const float* __restrict__ bt2,
    float* __restrict__ out) {
  int idx = blockIdx.x * 256 + threadIdx.x;
  if (idx >= NB * CB * TB * VB / 4) return;
  int o = (idx / (TB * VB / 4)) % CB;
  const float inv = 1.f / (8.f * 128.f * 25.f);
  float m = stats2[o] * inv;
  float var = stats2[96 + o] * inv - m * m;
  float a = g2[o] * rsqrtf(var + EPSB);
  float b = bt2[o] - m * a;
  f32x4 vin = reinterpret_cast<const f32x4*>(out_pre)[idx];
  f32x4 vo;
#pragma unroll
  for (int j = 0; j < 4; ++j) vo[j] = a * vin[j] + b;
  reinterpret_cast<f32x4*>(out)[idx] = vo;
}

extern "C" void kernel_launch(void* const* d_in, const int* in_sizes, int n_in,
                              void* d_out, int out_size, void* d_ws, size_t ws_size,
                              hipStream_t stream) {
  const float* x   = (const float*)d_in[0];
  const float* As  = (const float*)d_in[1];
  const float* Bs  = (const float*)d_in[2];
  const float* Ar  = (const float*)d_in[3];
  const float* Wm  = (const float*)d_in[4];
  const float* bm  = (const float*)d_in[5];
  const float* g1  = (const float*)d_in[6];
  const float* bt1 = (const float*)d_in[7];
  const float* Wo  = (const float*)d_in[8];
  const float* bo  = (const float*)d_in[9];
  const float* g2  = (const float*)d_in[10];
  const float* bt2 = (const float*)d_in[11];
  float* out = (float*)d_out;

  char* base = (char*)d_ws;
  unsigned short* HR   = (unsigned short*)base;                  // 14,745,600 B
  float* out_pre       = (float*)(base + 14745600);              //  9,830,400 B
  unsigned short* ABsw = (unsigned short*)(base + 24576000);     //    184,320 B
  unsigned short* Wsw  = (unsigned short*)(base + 24760320);     //    221,184 B
  unsigned short* Wosw = (unsigned short*)(base + 24981504);     //     55,296 B
  float* stats         = (float*)(base + 25036800);              //      1,536 B
  float* stats1 = stats, *stats2 = stats + 192;

  k0_init<<<432, 256, 0, stream>>>(As, Bs, Ar, Wm, Wo, ABsw, Wsw, Wosw, stats);
  k1t2<<<NB * TB / 2, 768, 0, stream>>>(x, ABsw, Wsw, bm, HR, stats1);
  k3n<<<NB * TB / 2, 768, 0, stream>>>(HR, stats1, g1, bt1, Wosw, bo, out_pre);
  k4_stats<<<CB * 4, 256, 0, stream>>>(out_pre, stats2);
  k5_bn2<<<(NB * CB * TB * VB / 4 + 255) / 256, 256, 0, stream>>>(out_pre, stats2, g2, bt2, out);
}